// Round 15
// baseline (148.962 us; speedup 1.0000x reference)
//
#include <hip/hip_runtime.h>
#include <hip/hip_bf16.h>

#define NMAX 64
#define LDA 65   // +1 pad: row scan = (i + c) % 32 banks -> 2-way aliasing (free)

typedef float f32x32 __attribute__((ext_vector_type(32)));

// ---- cross-lane helpers ----
__device__ __forceinline__ double readlane_d(double x, int l) {
    const int lo = __builtin_amdgcn_readlane(__double2loint(x), l);
    const int hi = __builtin_amdgcn_readlane(__double2hiint(x), l);
    return __hiloint2double(hi, lo);
}
__device__ __forceinline__ float readlane_f(float x, int l) {
    return __int_as_float(__builtin_amdgcn_readlane(__float_as_int(x), l));
}
template <int CTRL>
__device__ __forceinline__ unsigned dpp_umin(unsigned x) {
    const unsigned t = (unsigned)__builtin_amdgcn_update_dpp(0, (int)x, CTRL, 0xF, 0xF, true);
    return x < t ? x : t;          // folds to v_min_u32_dpp
}
__device__ __forceinline__ unsigned dpp_umin6(unsigned x) {  // lane63 = global min
    x = dpp_umin<0xB1>(x);  x = dpp_umin<0x4E>(x);
    x = dpp_umin<0x141>(x); x = dpp_umin<0x140>(x);
    x = dpp_umin<0x142>(x); x = dpp_umin<0x143>(x);
    return x;
}
template <int CTRL>
__device__ __forceinline__ double dpp_add_step(double x) {
    const int lo = __builtin_amdgcn_update_dpp(0, __double2loint(x), CTRL, 0xF, 0xF, true);
    const int hi = __builtin_amdgcn_update_dpp(0, __double2hiint(x), CTRL, 0xF, 0xF, true);
    return x + __hiloint2double(hi, lo);
}
__device__ __forceinline__ double wave_sum_f64(double x) {   // exact, each lane once
    x = dpp_add_step<0xB1>(x);  x = dpp_add_step<0x4E>(x);
    x = dpp_add_step<0x141>(x); x = dpp_add_step<0x140>(x);
    x = dpp_add_step<0x142>(x); x = dpp_add_step<0x143>(x);
    return readlane_d(x, 63);
}
// mask-lane ? a : b (mask = wave-uniform 64-bit value in SGPRs)
__device__ __forceinline__ unsigned sel_u32(unsigned long long m, unsigned a, unsigned b) {
    unsigned r;
    asm("v_cndmask_b32 %0, %1, %2, %3" : "=v"(r) : "v"(b), "v"(a), "s"(m));
    return r;
}
__device__ __forceinline__ float sel_f32(unsigned long long m, float a, float b) {
    return __int_as_float((int)sel_u32(m, (unsigned)__float_as_int(a),
                                          (unsigned)__float_as_int(b)));
}
__device__ __forceinline__ int sel_i32(unsigned long long m, int a, int b) {
    return (int)sel_u32(m, (unsigned)a, (unsigned)b);
}
// uniform dynamic extract from the 64-deep register column
__device__ __forceinline__ float mat_get(const f32x32& lo, const f32x32& hi, int rr) {
    const float aL = lo[rr & 31], aH = hi[rr & 31];
    return (rr & 32) ? aH : aL;
}

// One wave (64 lanes) per batch: Jonker-Volgenant LAP, distance formulation,
// full f32, register-resident matrix, FULL JV init, with PRECOMPUTED ARR BIDS:
// after column reduction + greedy matching, one parallel in-lane pass (lane i
// scans LDS row i; v[c] broadcast via readlane) computes every row's
// (min1, j1, min2, j2). The ARR cascade then consumes cached bids.
// STALENESS PROOF: cascade only DECREASES v, only at columns in `vchanged`.
// If j1 not in vchanged: r(i,j1) = -a - v[j1] is unchanged; every other
// column's reduced cost only rose => j1 still the argmin with the same u1,
// and stale u2 <= current second-min. Setting v[j1] -= (u2-u1), u[i] = u2:
// slack(i,j1) = (u1 + (u2-u1)) - u2 = 0 exactly; slack(i,j) >= cur2 - u2 >= 0.
// Tie path (u1==u2, j1 occupied -> j2) additionally needs j2 not in vchanged:
// then slack(i,j2) = u2 - u2 = 0 exactly, no v change. Previously matched
// edges keep slack 0 (their columns' v changes only when they are kicked).
// Invalid bids fall back to the R12 two-pass packed wave reduce. Any valid
// ARR sequence yields the unique optimum (absmax 0.0 across R8-R14).
__global__ __launch_bounds__(64, 2) void hung_loss_kernel(
    const float* __restrict__ pred, const float* __restrict__ gt,
    const int* __restrict__ n1s, const int* __restrict__ n2s,
    double* __restrict__ partial)
{
    const int b = blockIdx.x;
    const int lane = threadIdx.x & 63;
    const float* __restrict__ predb = pred + (size_t)b * NMAX * NMAX;
    const float* __restrict__ gtb   = gt   + (size_t)b * NMAX * NMAX;
    const int n1 = n1s[b];
    const int n2 = n2s[b];
    const bool trans = (n1 > n2);                  // lap requires n <= m
    const int n = trans ? n2 : n1;
    const int m = trans ? n1 : n2;
    const float FINF  = __int_as_float(0x7f800000);
    const float FNINF = __int_as_float(0xff800000);
    const unsigned NEGINF32 = 0xFF800000u;

    // ---- stage LAP matrix row-major into padded LDS (for the bid pass) ----
    __shared__ float A[NMAX * LDA];
    __shared__ int mincol[NMAX];
    mincol[lane] = 127;
    {
        const float4* p4 = (const float4*)predb;
        #pragma unroll
        for (int it = 0; it < 16; ++it) {
            const float4 val = p4[it * 64 + lane];
            const int r = it * 4 + (lane >> 4);    // source row in pred
            const int c = (lane & 15) * 4;         // source col in pred
            if (!trans) {
                A[r * LDA + c + 0] = val.x; A[r * LDA + c + 1] = val.y;
                A[r * LDA + c + 2] = val.z; A[r * LDA + c + 3] = val.w;
            } else {
                A[(c + 0) * LDA + r] = val.x; A[(c + 1) * LDA + r] = val.y;
                A[(c + 2) * LDA + r] = val.z; A[(c + 3) * LDA + r] = val.w;
            }
        }
    }

    // ---- load LAP matrix into registers: lane j holds lap[:, j] (64 f32) ----
    f32x32 alo, ahi;
    if (!trans) {                                  // lap == scores
        #pragma unroll
        for (int r = 0; r < 32; ++r) alo[r] = predb[r * NMAX + lane];
        #pragma unroll
        for (int r = 0; r < 32; ++r) ahi[r] = predb[(r + 32) * NMAX + lane];
    } else {                                       // lap = scores^T
        #pragma unroll
        for (int r = 0; r < 32; ++r) alo[r] = predb[lane * NMAX + r];
        #pragma unroll
        for (int r = 0; r < 32; ++r) ahi[r] = predb[lane * NMAX + 32 + r];
    }
    if (lane >= m) {                               // fake columns: cost -> -inf
        #pragma unroll
        for (int r = 0; r < 32; ++r) { alo[r] = FNINF; ahi[r] = FNINF; }
    }

    // ---- column reduction over real rows (r < n): v = -max, argmax row am ----
    float v;
    int am = 0;
    {
        float mx = FNINF;
        #pragma unroll
        for (int r = 0; r < 32; ++r) {
            const bool take = (r < n) && (alo[r] > mx);
            mx = take ? alo[r] : mx;
            am = take ? r : am;
        }
        #pragma unroll
        for (int r = 0; r < 32; ++r) {
            const bool take = ((r + 32) < n) && (ahi[r] > mx);
            mx = take ? ahi[r] : mx;
            am = take ? (r + 32) : am;
        }
        v = (lane < m) ? (-mx) : 0.0f;
    }

    // ---- greedy zero-edge matching: column j -> row am(j), first column wins
    __syncthreads();
    if (lane < m) atomicMin(&mincol[am], lane);
    __syncthreads();
    const bool matched = (lane < m) && (mincol[am] == lane);
    int p = matched ? (am + 1) : 0;                // column-side matching (1-based)
    const unsigned long long rowsM =
        __ballot((lane < n) && (mincol[lane] != 127));
    unsigned long long freerows =
        (~rowsM) & ((n == 64) ? ~0ull : ((1ull << n) - 1ull));

    float u = 0.0f;      // lane r owns u[r+1] (row dual)
    float uent = 0.0f;   // entry distance of row lane+1 (valid when on tree)
    float dsel = 0.0f;   // selected distance of column lane+1 (valid when used)
    const unsigned long long fake = (m < 64) ? (~0ull << m) : 0ull;
    const unsigned VMASK = 0xFFFFFFC0u;            // value part of packed key

    // ---- precompute per-row bids: lane i scans LDS row i; v[c] via readlane ----
    float bm1 = FINF, bm2 = FINF;
    int bj1 = 1, bj2 = 1;
    #pragma unroll
    for (int c = 0; c < NMAX; ++c) {
        const float vc = readlane_f(v, c);         // literal lane index
        const float a  = A[lane * LDA + c];        // 2-way bank alias: free
        float rc = fmaxf((0.0f - a) - vc, 0.0f);
        if ((fake >> c) & 1ull) rc = FINF;         // uniform: fake column
        const bool b1 = rc < bm1;
        const bool b2 = rc < bm2;
        bm2 = b1 ? bm1 : (b2 ? rc : bm2);
        bj2 = b1 ? bj1 : (b2 ? (c + 1) : bj2);
        bm1 = b1 ? rc : bm1;
        bj1 = b1 ? (c + 1) : bj1;
    }

    // ---- ARR cascade on cached bids (slow-path refresh when stale) ----
    {
        unsigned long long vchanged = 0ull;
        int steps = 0;
        while (freerows && steps < 192) {
            ++steps;
            const int i = __ffsll(freerows);       // 1-based free row
            freerows &= freerows - 1;
            int j1 = __builtin_amdgcn_readlane(bj1, i - 1);
            int j2 = __builtin_amdgcn_readlane(bj2, i - 1);
            float u1 = readlane_f(bm1, i - 1);
            float u2 = readlane_f(bm2, i - 1);
            bool tie = !(u1 < u2);
            const bool bad = ((vchanged >> (j1 - 1)) & 1ull) ||
                             (tie && ((vchanged >> (j2 - 1)) & 1ull));
            if (bad) {                             // refresh: R12 two-pass reduce
                const float aa = mat_get(alo, ahi, i - 1);
                const float r_ = fmaxf((0.0f - aa) - v, 0.0f);
                const unsigned key = (__float_as_uint(r_) & VMASK) | (unsigned)lane;
                const unsigned K1 =
                    (unsigned)__builtin_amdgcn_readlane((int)dpp_umin6(key), 63);
                j1 = (int)(K1 & 63u) + 1;
                const unsigned key2s = sel_u32(1ull << (j1 - 1), 0xFFFFFFFFu, key);
                const unsigned K2 =
                    (unsigned)__builtin_amdgcn_readlane((int)dpp_umin6(key2s), 63);
                j2 = (int)(K2 & 63u) + 1;
                u1 = __uint_as_float(K1 & VMASK);
                u2 = __uint_as_float(K2 & VMASK);
                tie = !(u1 < u2);
            }
            int jt = j1;
            int kick = __builtin_amdgcn_readlane(p, j1 - 1);
            if (!tie) {                            // unique min: tighten v[j1]
                v = sel_f32(1ull << (j1 - 1), v - (u2 - u1), v);
                vchanged |= 1ull << (j1 - 1);
            } else if (kick != 0) {                // tie and j1 taken: use j2
                jt = j2;
                kick = __builtin_amdgcn_readlane(p, j2 - 1);
            }
            p = sel_i32(1ull << (jt - 1), i, p);   // assign row i to column jt
            u = sel_f32(1ull << (i - 1), u2, u);   // u[i] = u2 (CS + feasible)
            if (kick != 0) freerows |= 1ull << (kick - 1);
        }
    }

    // ---- Dijkstra phases for remaining free rows (identical to R12) ----
    while (freerows) {
        const int i = __ffsll(freerows);           // 1-based free row
        freerows &= freerows - 1;
        unsigned long long um = 0ull;              // used (selected) columns
        unsigned long long rowm = 1ull << (i - 1); // rows on the tree
        float d = FINF;                            // tentative distances
        int way = 0;                               // tree parent column (0=root)
        int vj0 = 0;                               // previous j1 (VGPR copy)
        float s = 0.0f - readlane_f(u, i - 1);     // s = D(i0) - u0[i0]
        uent = sel_f32(rowm, 0.0f, uent);          // root row entry distance = 0
        float aval = mat_get(alo, ahi, i - 1);     // row i (fake lanes -inf)
        int j1f = 0;
        float DT = 0.0f;
        for (int guard = 0; guard < NMAX; ++guard) {
            const float r_ = (0.0f - aval) - v;    // used/fake -> +inf
            const float cur = fmaxf(r_ + s, 0.0f); // clamp: keys stay ordered
            const float dn = fminf(d, cur);
            const unsigned key = (__float_as_uint(dn) & VMASK) | (unsigned)lane;
            const unsigned K = (unsigned)__builtin_amdgcn_readlane((int)dpp_umin6(key), 63);
            const int j1 = (int)(K & 63u) + 1;
            const int i0n = __builtin_amdgcn_readlane(p, j1 - 1); // p[j1]; 0 => free
            const float H = __uint_as_float(K & VMASK);           // delta (trunc)
            const unsigned long long mj = 1ull << (j1 - 1);
            const bool lt = cur < d;
            way  = lt ? vj0 : way;
            dsel = sel_f32(mj, dn, dsel);          // record selected distance
            d    = sel_f32(mj, FINF, dn);          // destroy selected column
            if (i0n == 0) { j1f = j1; DT = H; break; }
            um |= mj;
            rowm |= 1ull << (i0n - 1);
            uent = sel_f32(1ull << (i0n - 1), H, uent);   // row entry distance
            s = H - readlane_f(u, i0n - 1);
            aval = mat_get(alo, ahi, i0n - 1);
            aval = __int_as_float((int)sel_u32(um, NEGINF32, __float_as_int(aval)));
            vj0 = j1;
        }
        // ---- phase-end dual updates (equivalent to per-iteration +=/-=) ----
        v = sel_f32(um,   v + (dsel - DT), v);     // used columns
        u = sel_f32(rowm, u + (DT - uent), u);     // tree rows
        // ---- augment along way[] back to the root ----
        int j0 = j1f;
        while (j0 > 0) {
            const int j1w = __builtin_amdgcn_readlane(way, j0 - 1);
            const int newp = (j1w == 0) ? i : __builtin_amdgcn_readlane(p, j1w - 1);
            p = sel_i32(1ull << (j0 - 1), newp, p);
            j0 = j1w;
        }
    }

    // ---- fused loss: dis[i][j] from lane-held p; BCE in f32 like reference ----
    double lsum = 0.0;
    if (!trans) {
        #pragma unroll
        for (int i2 = 0; i2 < NMAX; ++i2) {
            const float pv = (i2 < 32) ? alo[i2] : ahi[i2 - 32];   // static extract
            const float gv = gtb[i2 * NMAX + lane];
            const float dis = (p == i2 + 1) ? 1.0f : 0.0f;
            float ali = dis + gv;
            if (ali > 1.0f) ali = 0.9f;
            const float pp = ali * pv;
            const float gg = ali * gv;
            const float lp  = fmaxf(logf(pp),    -100.0f);
            const float l1p = fmaxf(log1pf(-pp), -100.0f);
            const float bce = -(gg * lp + (1.0f - gg) * l1p);
            if (i2 < n1 && lane < n2) lsum += (double)bce;
        }
    } else {
        for (int i2 = 0; i2 < NMAX; ++i2) {
            const float pv = predb[i2 * NMAX + lane];
            const float gv = gtb[i2 * NMAX + lane];
            const int pi = __builtin_amdgcn_readlane(p, i2);
            const float dis = (pi - 1 == lane) ? 1.0f : 0.0f;
            float ali = dis + gv;
            if (ali > 1.0f) ali = 0.9f;
            const float pp = ali * pv;
            const float gg = ali * gv;
            const float lp  = fmaxf(logf(pp),    -100.0f);
            const float l1p = fmaxf(log1pf(-pp), -100.0f);
            const float bce = -(gg * lp + (1.0f - gg) * l1p);
            if (i2 < n1 && lane < n2) lsum += (double)bce;
        }
    }
    const double tsum = wave_sum_f64(lsum);
    if (lane == 0) partial[b] = tsum;
}

__global__ __launch_bounds__(256) void finalize_kernel(
    const double* __restrict__ partial, const int* __restrict__ n1s,
    float* __restrict__ out, int B)
{
    __shared__ double sred[256];
    __shared__ int    nred[256];
    const int t = threadIdx.x;
    double s = 0.0;
    int ns = 0;
    for (int bb = t; bb < B; bb += 256) { s += partial[bb]; ns += n1s[bb]; }
    sred[t] = s; nred[t] = ns;
    __syncthreads();
    for (int off = 128; off >= 1; off >>= 1) {
        if (t < off) { sred[t] += sred[t + off]; nred[t] += nred[t + off]; }
        __syncthreads();
    }
    if (t == 0) out[0] = (float)sred[0] / (float)nred[0];
}

extern "C" void kernel_launch(void* const* d_in, const int* in_sizes, int n_in,
                              void* d_out, int out_size, void* d_ws, size_t ws_size,
                              hipStream_t stream) {
    const float* pred = (const float*)d_in[0];   // [B,64,64] f32
    const float* gt   = (const float*)d_in[1];   // [B,64,64] f32
    const int* n1s    = (const int*)d_in[2];     // [B] i32
    const int* n2s    = (const int*)d_in[3];     // [B] i32
    float* out = (float*)d_out;                  // scalar f32
    double* partial = (double*)d_ws;             // B doubles (16 KB)
    const int B = in_sizes[2];

    hung_loss_kernel<<<B, 64, 0, stream>>>(pred, gt, n1s, n2s, partial);
    finalize_kernel<<<1, 256, 0, stream>>>(partial, n1s, out, B);
}

// Round 16
// 108.834 us; speedup vs baseline: 1.3687x; 1.3687x over previous
//
#include <hip/hip_runtime.h>
#include <hip/hip_bf16.h>

#define NMAX 64

typedef float f32x32 __attribute__((ext_vector_type(32)));

// ---- cross-lane helpers ----
__device__ __forceinline__ double readlane_d(double x, int l) {
    const int lo = __builtin_amdgcn_readlane(__double2loint(x), l);
    const int hi = __builtin_amdgcn_readlane(__double2hiint(x), l);
    return __hiloint2double(hi, lo);
}
__device__ __forceinline__ float readlane_f(float x, int l) {
    return __int_as_float(__builtin_amdgcn_readlane(__float_as_int(x), l));
}
template <int CTRL>
__device__ __forceinline__ unsigned dpp_umin(unsigned x) {
    const unsigned t = (unsigned)__builtin_amdgcn_update_dpp(0, (int)x, CTRL, 0xF, 0xF, true);
    return x < t ? x : t;          // folds to v_min_u32_dpp
}
__device__ __forceinline__ unsigned dpp_umin6(unsigned x) {  // lane63 = global min
    x = dpp_umin<0xB1>(x);  x = dpp_umin<0x4E>(x);
    x = dpp_umin<0x141>(x); x = dpp_umin<0x140>(x);
    x = dpp_umin<0x142>(x); x = dpp_umin<0x143>(x);
    return x;
}
// pair (min1,min2) DPP step: combine own pair with partner's pair
template <int CTRL>
__device__ __forceinline__ void pair_step(unsigned& x1, unsigned& x2) {
    const unsigned y1 = (unsigned)__builtin_amdgcn_update_dpp(0, (int)x1, CTRL, 0xF, 0xF, true);
    const unsigned y2 = (unsigned)__builtin_amdgcn_update_dpp(0, (int)x2, CTRL, 0xF, 0xF, true);
    const unsigned lo  = x1 < y1 ? x1 : y1;
    const unsigned hi  = x1 < y1 ? y1 : x1;
    const unsigned mn2 = x2 < y2 ? x2 : y2;
    x1 = lo;
    x2 = hi < mn2 ? hi : mn2;
}
// two smallest keys across the wave in ONE 6-step chain (lane63 -> K1,K2).
// Coverage: xor steps merge disjoint groups; bcast15 then bcast31 merge
// rows without double-counting -> lane63's pair covers all 64 lanes once.
__device__ __forceinline__ void dpp_umin6_pair(unsigned key, unsigned& K1, unsigned& K2) {
    unsigned x1 = key, x2 = 0xFFFFFFFFu;
    pair_step<0xB1>(x1, x2);  pair_step<0x4E>(x1, x2);
    pair_step<0x141>(x1, x2); pair_step<0x140>(x1, x2);
    pair_step<0x142>(x1, x2); pair_step<0x143>(x1, x2);
    K1 = (unsigned)__builtin_amdgcn_readlane((int)x1, 63);
    K2 = (unsigned)__builtin_amdgcn_readlane((int)x2, 63);
}
template <int CTRL>
__device__ __forceinline__ double dpp_add_step(double x) {
    const int lo = __builtin_amdgcn_update_dpp(0, __double2loint(x), CTRL, 0xF, 0xF, true);
    const int hi = __builtin_amdgcn_update_dpp(0, __double2hiint(x), CTRL, 0xF, 0xF, true);
    return x + __hiloint2double(hi, lo);
}
__device__ __forceinline__ double wave_sum_f64(double x) {   // exact, each lane once
    x = dpp_add_step<0xB1>(x);  x = dpp_add_step<0x4E>(x);
    x = dpp_add_step<0x141>(x); x = dpp_add_step<0x140>(x);
    x = dpp_add_step<0x142>(x); x = dpp_add_step<0x143>(x);
    return readlane_d(x, 63);
}
// mask-lane ? a : b (mask = wave-uniform 64-bit value in SGPRs)
__device__ __forceinline__ unsigned sel_u32(unsigned long long m, unsigned a, unsigned b) {
    unsigned r;
    asm("v_cndmask_b32 %0, %1, %2, %3" : "=v"(r) : "v"(b), "v"(a), "s"(m));
    return r;
}
__device__ __forceinline__ float sel_f32(unsigned long long m, float a, float b) {
    return __int_as_float((int)sel_u32(m, (unsigned)__float_as_int(a),
                                          (unsigned)__float_as_int(b)));
}
__device__ __forceinline__ int sel_i32(unsigned long long m, int a, int b) {
    return (int)sel_u32(m, (unsigned)a, (unsigned)b);
}
// uniform dynamic extract from the 64-deep register column
__device__ __forceinline__ float mat_get(const f32x32& lo, const f32x32& hi, int rr) {
    const float aL = lo[rr & 31], aH = hi[rr & 31];
    return (rr & 32) ? aH : aL;
}

// One wave (64 lanes) per batch: Jonker-Volgenant LAP, distance formulation,
// full f32, register-resident matrix, FULL JV init (column reduction + greedy
// zero matching + augmenting row reduction). ARR uses the single-chain PAIR
// reduce (two smallest packed keys in one 6-step DPP chain) — bit-identical
// decisions to R12's two-pass (keys are distinct), half the chain latency.
// Dijkstra phases, init, and epilogue identical to R12 (verified absmax 0.0).
__global__ __launch_bounds__(64, 2) void hung_loss_kernel(
    const float* __restrict__ pred, const float* __restrict__ gt,
    const int* __restrict__ n1s, const int* __restrict__ n2s,
    double* __restrict__ partial)
{
    const int b = blockIdx.x;
    const int lane = threadIdx.x & 63;
    const float* __restrict__ predb = pred + (size_t)b * NMAX * NMAX;
    const float* __restrict__ gtb   = gt   + (size_t)b * NMAX * NMAX;
    const int n1 = n1s[b];
    const int n2 = n2s[b];
    const bool trans = (n1 > n2);                  // lap requires n <= m
    const int n = trans ? n2 : n1;
    const int m = trans ? n1 : n2;
    const float FINF  = __int_as_float(0x7f800000);
    const float FNINF = __int_as_float(0xff800000);
    const unsigned NEGINF32 = 0xFF800000u;

    // ---- load LAP matrix into registers: lane j holds lap[:, j] (64 f32) ----
    f32x32 alo, ahi;
    if (!trans) {                                  // lap == scores
        #pragma unroll
        for (int r = 0; r < 32; ++r) alo[r] = predb[r * NMAX + lane];
        #pragma unroll
        for (int r = 0; r < 32; ++r) ahi[r] = predb[(r + 32) * NMAX + lane];
    } else {                                       // lap = scores^T
        #pragma unroll
        for (int r = 0; r < 32; ++r) alo[r] = predb[lane * NMAX + r];
        #pragma unroll
        for (int r = 0; r < 32; ++r) ahi[r] = predb[lane * NMAX + 32 + r];
    }
    if (lane >= m) {                               // fake columns: cost -> -inf
        #pragma unroll
        for (int r = 0; r < 32; ++r) { alo[r] = FNINF; ahi[r] = FNINF; }
    }

    // ---- column reduction over real rows (r < n): v = -max, argmax row am ----
    float v;
    int am = 0;
    {
        float mx = FNINF;
        #pragma unroll
        for (int r = 0; r < 32; ++r) {
            const bool take = (r < n) && (alo[r] > mx);
            mx = take ? alo[r] : mx;
            am = take ? r : am;
        }
        #pragma unroll
        for (int r = 0; r < 32; ++r) {
            const bool take = ((r + 32) < n) && (ahi[r] > mx);
            mx = take ? ahi[r] : mx;
            am = take ? (r + 32) : am;
        }
        v = (lane < m) ? (-mx) : 0.0f;
    }

    // ---- greedy zero-edge matching: column j -> row am(j), first column wins
    __shared__ int mincol[NMAX];
    mincol[lane] = 127;
    __syncthreads();
    if (lane < m) atomicMin(&mincol[am], lane);
    __syncthreads();
    const bool matched = (lane < m) && (mincol[am] == lane);
    int p = matched ? (am + 1) : 0;                // column-side matching (1-based)
    const unsigned long long rowsM =
        __ballot((lane < n) && (mincol[lane] != 127));
    unsigned long long freerows =
        (~rowsM) & ((n == 64) ? ~0ull : ((1ull << n) - 1ull));

    float u = 0.0f;      // lane r owns u[r+1] (row dual)
    float uent = 0.0f;   // entry distance of row lane+1 (valid when on tree)
    float dsel = 0.0f;   // selected distance of column lane+1 (valid when used)
    const unsigned VMASK = 0xFFFFFFC0u;            // value part of packed key

    // ---- augmenting row reduction (ARR), pair-reduce selection ----
    {
        int steps = 0;
        while (freerows && steps < 128) {
            ++steps;
            const int i = __ffsll(freerows);       // 1-based free row
            freerows &= freerows - 1;
            const float a = mat_get(alo, ahi, i - 1);
            float r_ = (0.0f - a) - v;             // reduced cost (u_i treated 0)
            r_ = fmaxf(r_, 0.0f);                  // clamp drift; keeps uint order
            const unsigned key1 = (__float_as_uint(r_) & VMASK) | (unsigned)lane;
            unsigned K1, K2;
            dpp_umin6_pair(key1, K1, K2);          // two smallest keys, one chain
            const int j1 = (int)(K1 & 63u) + 1;
            const unsigned u1b = K1 & VMASK, u2b = K2 & VMASK;
            const float u2f = __uint_as_float(u2b);
            int jt = j1;
            int i0k = __builtin_amdgcn_readlane(p, j1 - 1);
            if (u1b < u2b) {                       // unique min: tighten v[j1]
                const float u1f = __uint_as_float(u1b);
                v = sel_f32(1ull << (j1 - 1), v - (u2f - u1f), v);
            } else if (i0k != 0) {                 // tie and j1 taken: use j2
                jt = (int)(K2 & 63u) + 1;
                i0k = __builtin_amdgcn_readlane(p, jt - 1);
            }
            p = sel_i32(1ull << (jt - 1), i, p);   // assign row i to column jt
            u = sel_f32(1ull << (i - 1), u2f, u);  // u[i] = u2 (CS + feasible)
            if (i0k != 0) freerows |= 1ull << (i0k - 1);   // kicked row rejoins
        }
    }

    // ---- Dijkstra phases for remaining free rows (identical to R12) ----
    while (freerows) {
        const int i = __ffsll(freerows);           // 1-based free row
        freerows &= freerows - 1;
        unsigned long long um = 0ull;              // used (selected) columns
        unsigned long long rowm = 1ull << (i - 1); // rows on the tree
        float d = FINF;                            // tentative distances
        int way = 0;                               // tree parent column (0=root)
        int vj0 = 0;                               // previous j1 (VGPR copy)
        float s = 0.0f - readlane_f(u, i - 1);     // s = D(i0) - u0[i0]
        uent = sel_f32(rowm, 0.0f, uent);          // root row entry distance = 0
        float aval = mat_get(alo, ahi, i - 1);     // row i (fake lanes -inf)
        int j1f = 0;
        float DT = 0.0f;
        for (int guard = 0; guard < NMAX; ++guard) {
            const float r_ = (0.0f - aval) - v;    // used/fake -> +inf
            const float cur = fmaxf(r_ + s, 0.0f); // clamp: keys stay ordered
            const float dn = fminf(d, cur);
            const unsigned key = (__float_as_uint(dn) & VMASK) | (unsigned)lane;
            const unsigned K = (unsigned)__builtin_amdgcn_readlane((int)dpp_umin6(key), 63);
            const int j1 = (int)(K & 63u) + 1;
            const int i0n = __builtin_amdgcn_readlane(p, j1 - 1); // p[j1]; 0 => free
            const float H = __uint_as_float(K & VMASK);           // delta (trunc)
            const unsigned long long mj = 1ull << (j1 - 1);
            const bool lt = cur < d;
            way  = lt ? vj0 : way;
            dsel = sel_f32(mj, dn, dsel);          // record selected distance
            d    = sel_f32(mj, FINF, dn);          // destroy selected column
            if (i0n == 0) { j1f = j1; DT = H; break; }
            um |= mj;
            rowm |= 1ull << (i0n - 1);
            uent = sel_f32(1ull << (i0n - 1), H, uent);   // row entry distance
            s = H - readlane_f(u, i0n - 1);
            aval = mat_get(alo, ahi, i0n - 1);
            aval = __int_as_float((int)sel_u32(um, NEGINF32, __float_as_int(aval)));
            vj0 = j1;
        }
        // ---- phase-end dual updates (equivalent to per-iteration +=/-=) ----
        v = sel_f32(um,   v + (dsel - DT), v);     // used columns
        u = sel_f32(rowm, u + (DT - uent), u);     // tree rows
        // ---- augment along way[] back to the root ----
        int j0 = j1f;
        while (j0 > 0) {
            const int j1w = __builtin_amdgcn_readlane(way, j0 - 1);
            const int newp = (j1w == 0) ? i : __builtin_amdgcn_readlane(p, j1w - 1);
            p = sel_i32(1ull << (j0 - 1), newp, p);
            j0 = j1w;
        }
    }

    // ---- fused loss: dis[i][j] from lane-held p; BCE in f32 like reference ----
    double lsum = 0.0;
    if (!trans) {
        #pragma unroll
        for (int i2 = 0; i2 < NMAX; ++i2) {
            const float pv = (i2 < 32) ? alo[i2] : ahi[i2 - 32];   // static extract
            const float gv = gtb[i2 * NMAX + lane];
            const float dis = (p == i2 + 1) ? 1.0f : 0.0f;
            float ali = dis + gv;
            if (ali > 1.0f) ali = 0.9f;
            const float pp = ali * pv;
            const float gg = ali * gv;
            const float lp  = fmaxf(logf(pp),    -100.0f);
            const float l1p = fmaxf(log1pf(-pp), -100.0f);
            const float bce = -(gg * lp + (1.0f - gg) * l1p);
            if (i2 < n1 && lane < n2) lsum += (double)bce;
        }
    } else {
        for (int i2 = 0; i2 < NMAX; ++i2) {
            const float pv = predb[i2 * NMAX + lane];
            const float gv = gtb[i2 * NMAX + lane];
            const int pi = __builtin_amdgcn_readlane(p, i2);
            const float dis = (pi - 1 == lane) ? 1.0f : 0.0f;
            float ali = dis + gv;
            if (ali > 1.0f) ali = 0.9f;
            const float pp = ali * pv;
            const float gg = ali * gv;
            const float lp  = fmaxf(logf(pp),    -100.0f);
            const float l1p = fmaxf(log1pf(-pp), -100.0f);
            const float bce = -(gg * lp + (1.0f - gg) * l1p);
            if (i2 < n1 && lane < n2) lsum += (double)bce;
        }
    }
    const double tsum = wave_sum_f64(lsum);
    if (lane == 0) partial[b] = tsum;
}

__global__ __launch_bounds__(256) void finalize_kernel(
    const double* __restrict__ partial, const int* __restrict__ n1s,
    float* __restrict__ out, int B)
{
    __shared__ double sred[256];
    __shared__ int    nred[256];
    const int t = threadIdx.x;
    double s = 0.0;
    int ns = 0;
    for (int bb = t; bb < B; bb += 256) { s += partial[bb]; ns += n1s[bb]; }
    sred[t] = s; nred[t] = ns;
    __syncthreads();
    for (int off = 128; off >= 1; off >>= 1) {
        if (t < off) { sred[t] += sred[t + off]; nred[t] += nred[t + off]; }
        __syncthreads();
    }
    if (t == 0) out[0] = (float)sred[0] / (float)nred[0];
}

extern "C" void kernel_launch(void* const* d_in, const int* in_sizes, int n_in,
                              void* d_out, int out_size, void* d_ws, size_t ws_size,
                              hipStream_t stream) {
    const float* pred = (const float*)d_in[0];   // [B,64,64] f32
    const float* gt   = (const float*)d_in[1];   // [B,64,64] f32
    const int* n1s    = (const int*)d_in[2];     // [B] i32
    const int* n2s    = (const int*)d_in[3];     // [B] i32
    float* out = (float*)d_out;                  // scalar f32
    double* partial = (double*)d_ws;             // B doubles (16 KB)
    const int B = in_sizes[2];

    hung_loss_kernel<<<B, 64, 0, stream>>>(pred, gt, n1s, n2s, partial);
    finalize_kernel<<<1, 256, 0, stream>>>(partial, n1s, out, B);
}